// Round 3
// baseline (274.452 us; speedup 1.0000x reference)
//
#include <hip/hip_runtime.h>
#include <hip/hip_bf16.h>

typedef __bf16 bf16;
typedef __attribute__((ext_vector_type(8))) __bf16 bf16x8;
typedef __attribute__((ext_vector_type(4))) __bf16 bf16x4;
typedef __attribute__((ext_vector_type(4))) float f32x4;

#define GLOAD_LDS16(g, l) __builtin_amdgcn_global_load_lds( \
    (const __attribute__((address_space(1))) void*)(g),     \
    (__attribute__((address_space(3))) void*)(l), 16, 0, 0)

constexpr int MTOT = 4096;   // BS*QLEN
constexpr int DIMC = 1024;
constexpr int QL   = 2048;
constexpr int NH   = 16;
constexpr int HD   = 64;
constexpr float LOG2E = 1.44269504088896340736f;

// ---------------- fp32 -> bf16 convert ----------------
__global__ void cvt_f32_bf16(const float* __restrict__ src, bf16* __restrict__ dst, int n) {
  int i = (blockIdx.x * blockDim.x + threadIdx.x) * 4;
  if (i < n) {
    float4 f = *reinterpret_cast<const float4*>(src + i);
    bf16x4 v;
    v[0] = (bf16)f.x; v[1] = (bf16)f.y; v[2] = (bf16)f.z; v[3] = (bf16)f.w;
    *reinterpret_cast<bf16x4*>(dst + i) = v;
  }
}

// ---------------- BT GEMM: C[m][n] = (sum_k A[m][k]*B[n][k] + bias)*scale ----
template<bool BF16OUT>
__global__ __launch_bounds__(256) void gemm_bt(
    const bf16* __restrict__ A,
    const bf16* __restrict__ W0, const bf16* __restrict__ W1, const bf16* __restrict__ W2,
    const float* __restrict__ b0, const float* __restrict__ b1, const float* __restrict__ b2,
    void* __restrict__ D0, void* __restrict__ D1, void* __restrict__ D2,
    float scale0)
{
  __shared__ __align__(16) bf16 As[128 * 64];
  __shared__ __align__(16) bf16 Bs[128 * 64];

  const bf16* Bm; const float* bias; void* D; float scale = 1.f;
  const int z = blockIdx.z;
  if (z == 0)      { Bm = W0; bias = b0; D = D0; scale = scale0; }
  else if (z == 1) { Bm = W1; bias = b1; D = D1; }
  else             { Bm = W2; bias = b2; D = D2; }

  const int tid  = threadIdx.x;
  const int w    = tid >> 6, lane = tid & 63;
  const int gm0  = blockIdx.x * 128, gn0 = blockIdx.y * 128;
  const int wr   = (w >> 1) * 64, wc = (w & 1) * 64;
  const int lr   = lane & 15;
  const int lk   = (lane >> 4) * 8;
  const int srow = (w << 3) + (lane >> 3);
  const int scol = (lane & 7) * 8;

  f32x4 acc[4][4] = {};

  for (int kt = 0; kt < DIMC / 64; ++kt) {
    __syncthreads();
    const int k0 = kt * 64;
#pragma unroll
    for (int p = 0; p < 4; ++p) {
      const int r = p * 32 + srow;
      GLOAD_LDS16(A  + (size_t)(gm0 + r) * DIMC + k0 + scol, &As[(p * 32 + (w << 3)) * 64]);
      GLOAD_LDS16(Bm + (size_t)(gn0 + r) * DIMC + k0 + scol, &Bs[(p * 32 + (w << 3)) * 64]);
    }
    asm volatile("s_waitcnt vmcnt(0)" ::: "memory");
    __syncthreads();

#pragma unroll
    for (int kk = 0; kk < 2; ++kk) {
      bf16x8 af[4], bfv[4];
#pragma unroll
      for (int mf = 0; mf < 4; ++mf)
        af[mf] = *reinterpret_cast<const bf16x8*>(&As[(wr + mf * 16 + lr) * 64 + kk * 32 + lk]);
#pragma unroll
      for (int nf = 0; nf < 4; ++nf)
        bfv[nf] = *reinterpret_cast<const bf16x8*>(&Bs[(wc + nf * 16 + lr) * 64 + kk * 32 + lk]);
#pragma unroll
      for (int mf = 0; mf < 4; ++mf)
#pragma unroll
        for (int nf = 0; nf < 4; ++nf)
          acc[mf][nf] = __builtin_amdgcn_mfma_f32_16x16x32_bf16(af[mf], bfv[nf], acc[mf][nf], 0, 0, 0);
    }
  }

  const int orow = (lane >> 4) * 4;
#pragma unroll
  for (int mf = 0; mf < 4; ++mf) {
#pragma unroll
    for (int nf = 0; nf < 4; ++nf) {
      const int c = gn0 + wc + nf * 16 + lr;
      const float bv = bias[c];
#pragma unroll
      for (int i = 0; i < 4; ++i) {
        const int r = gm0 + wr + mf * 16 + orow + i;
        const float v = (acc[mf][nf][i] + bv) * scale;
        if constexpr (BF16OUT) ((bf16*)D)[(size_t)r * DIMC + c]  = (bf16)v;
        else                   ((float*)D)[(size_t)r * DIMC + c] = v;
      }
    }
  }
}

// ---------------- V transpose: V[b*QL+kv][h*64+d] -> Vt[(bh*64+d)][kv] ----------------
__global__ __launch_bounds__(256) void transpose_v(
    const bf16* __restrict__ V, bf16* __restrict__ Vt)
{
  __shared__ __align__(16) bf16 Vs[64 * 72];
  const int tid = threadIdx.x;
  const int kvt = blockIdx.x, bh = blockIdx.y;
  const int b = bh >> 4, h = bh & 15;
  const int kv0 = kvt * 64;
  const int rr = tid >> 3, c8 = (tid & 7) * 8;
#pragma unroll
  for (int p = 0; p < 2; ++p) {
    const int r = p * 32 + rr;
    *reinterpret_cast<bf16x8*>(&Vs[r * 72 + c8]) =
      *reinterpret_cast<const bf16x8*>(&V[((size_t)b * QL + kv0 + r) * DIMC + h * HD + c8]);
  }
  __syncthreads();
#pragma unroll
  for (int p = 0; p < 2; ++p) {
    const int d = p * 32 + rr;
    bf16x8 v;
#pragma unroll
    for (int j = 0; j < 8; ++j) v[j] = Vs[(c8 + j) * 72 + d];
    *reinterpret_cast<bf16x8*>(&Vt[((size_t)bh * HD + d) * QL + kv0 + c8]) = v;
  }
}

// ---------------- Flash attention, no-staging version ----------------
// 128 threads = 2 independent waves; wave handles 32 q rows (2 fragment sets).
// K and Vt B-fragments loaded directly from global (L1/L2-resident tiles).
// No __syncthreads anywhere; only LDS use is the per-wave P round-trip.
__global__ __launch_bounds__(128, 2) void attn_fwd(
    const bf16* __restrict__ Q, const bf16* __restrict__ K, const bf16* __restrict__ Vt,
    const float* __restrict__ mask, bf16* __restrict__ ctx)
{
  __shared__ __align__(16) bf16 Ps[2][32 * 72];

  const int tid = threadIdx.x, w = tid >> 6, lane = tid & 63;
  const int bid = blockIdx.x;
  const int logical = (bid & 7) * 128 + (bid >> 3);   // bijective: 1024 % 8 == 0
  const int qt = logical & 31, bh = logical >> 5;     // 4 bh per XCD -> 2MB KV set in L2
  const int b = bh >> 4, h = bh & 15;
  const int lr = lane & 15, lk = (lane >> 4) * 8;

  // Q fragments (A operand): rows qt*64 + w*32 + s*16 + lr  (scale folded in GEMM)
  bf16x8 aq[2][2];
#pragma unroll
  for (int s = 0; s < 2; ++s) {
    const size_t qr = (size_t)b * QL + qt * 64 + w * 32 + s * 16 + lr;
    const bf16* qp = Q + qr * DIMC + h * HD + lk;
    aq[s][0] = *reinterpret_cast<const bf16x8*>(qp);
    aq[s][1] = *reinterpret_cast<const bf16x8*>(qp + 32);
  }

  const bf16*  kp = K  + ((size_t)b * QL + lr) * DIMC + h * HD + lk;
  const bf16*  vp = Vt + ((size_t)bh * HD + lr) * QL + lk;
  const float* mp = mask + b * QL + lr;

  float m_i[2][4], l_i[2][4];
  f32x4 acc_o[2][4] = {};
#pragma unroll
  for (int s = 0; s < 2; ++s)
#pragma unroll
    for (int i = 0; i < 4; ++i) { m_i[s][i] = -INFINITY; l_i[s][i] = 0.f; }

  for (int t = 0; t < QL / 64; ++t) {
    const bf16* kpt = kp + (size_t)t * 64 * DIMC;

    // S = Q K^T   (B-frags straight from global: 16 rows x 64B lines)
    f32x4 sacc[2][4] = {};
#pragma unroll
    for (int kk = 0; kk < 2; ++kk) {
      bf16x8 bk[4];
#pragma unroll
      for (int nf = 0; nf < 4; ++nf)
        bk[nf] = *reinterpret_cast<const bf16x8*>(kpt + (size_t)nf * 16 * DIMC + kk * 32);
#pragma unroll
      for (int s = 0; s < 2; ++s)
#pragma unroll
        for (int nf = 0; nf < 4; ++nf)
          sacc[s][nf] = __builtin_amdgcn_mfma_f32_16x16x32_bf16(aq[s][kk], bk[nf], sacc[s][nf], 0, 0, 0);
    }

    float mk[4];
#pragma unroll
    for (int nf = 0; nf < 4; ++nf) mk[nf] = mp[t * 64 + nf * 16] * LOG2E;

    // online softmax in log2 space (Q pre-scaled by 0.125*log2e)
#pragma unroll
    for (int s = 0; s < 2; ++s) {
#pragma unroll
      for (int i = 0; i < 4; ++i) {
        const float s0 = sacc[s][0][i] + mk[0], s1 = sacc[s][1][i] + mk[1];
        const float s2 = sacc[s][2][i] + mk[2], s3 = sacc[s][3][i] + mk[3];
        float mx = fmaxf(fmaxf(s0, s1), fmaxf(s2, s3));
#pragma unroll
        for (int off = 1; off < 16; off <<= 1) mx = fmaxf(mx, __shfl_xor(mx, off, 64));
        const float mnew = fmaxf(m_i[s][i], mx);
        const float alpha = exp2f(m_i[s][i] - mnew);
        const float p0 = exp2f(s0 - mnew), p1 = exp2f(s1 - mnew);
        const float p2 = exp2f(s2 - mnew), p3 = exp2f(s3 - mnew);
        const int prow = s * 16 + (lane >> 4) * 4 + i;
        bf16* pp = &Ps[w][prow * 72 + lr];
        pp[0] = (bf16)p0; pp[16] = (bf16)p1; pp[32] = (bf16)p2; pp[48] = (bf16)p3;
        float rs = p0 + p1 + p2 + p3;
#pragma unroll
        for (int off = 1; off < 16; off <<= 1) rs += __shfl_xor(rs, off, 64);
        l_i[s][i] = l_i[s][i] * alpha + rs;
        m_i[s][i] = mnew;
#pragma unroll
        for (int df = 0; df < 4; ++df) acc_o[s][df][i] *= alpha;
      }
    }

    // O += P V   (Vt B-frags from global; P via per-wave LDS round-trip)
#pragma unroll
    for (int kk = 0; kk < 2; ++kk) {
      bf16x8 bv[4];
#pragma unroll
      for (int df = 0; df < 4; ++df)
        bv[df] = *reinterpret_cast<const bf16x8*>(vp + (size_t)df * 16 * QL + t * 64 + kk * 32);
      const bf16x8 ap0 = *reinterpret_cast<const bf16x8*>(&Ps[w][(0 * 16 + lr) * 72 + kk * 32 + lk]);
      const bf16x8 ap1 = *reinterpret_cast<const bf16x8*>(&Ps[w][(1 * 16 + lr) * 72 + kk * 32 + lk]);
#pragma unroll
      for (int df = 0; df < 4; ++df) {
        acc_o[0][df] = __builtin_amdgcn_mfma_f32_16x16x32_bf16(ap0, bv[df], acc_o[0][df], 0, 0, 0);
        acc_o[1][df] = __builtin_amdgcn_mfma_f32_16x16x32_bf16(ap1, bv[df], acc_o[1][df], 0, 0, 0);
      }
    }
  }

  // epilogue
#pragma unroll
  for (int s = 0; s < 2; ++s) {
#pragma unroll
    for (int i = 0; i < 4; ++i) {
      const float inv = 1.0f / l_i[s][i];
      const size_t r = (size_t)b * QL + qt * 64 + w * 32 + s * 16 + (lane >> 4) * 4 + i;
#pragma unroll
      for (int df = 0; df < 4; ++df)
        ctx[r * DIMC + h * HD + df * 16 + lr] = (bf16)(acc_o[s][df][i] * inv);
    }
  }
}

// ---------------- launch ----------------
extern "C" void kernel_launch(void* const* d_in, const int* in_sizes, int n_in,
                              void* d_out, int out_size, void* d_ws, size_t ws_size,
                              hipStream_t stream) {
  const float* x    = (const float*)d_in[0];
  const float* mask = (const float*)d_in[1];
  const float* qw = (const float*)d_in[2]; const float* qb = (const float*)d_in[3];
  const float* kw = (const float*)d_in[4]; const float* kb = (const float*)d_in[5];
  const float* vw = (const float*)d_in[6]; const float* vb = (const float*)d_in[7];
  const float* ow = (const float*)d_in[8]; const float* ob = (const float*)d_in[9];
  float* out = (float*)d_out;

  // workspace layout (bf16 elements), total 48 MB; ctx aliases V (attn reads Vt only)
  bf16* Xb  = (bf16*)d_ws;
  bf16* Wqb = Xb  + (size_t)MTOT * DIMC;
  bf16* Wkb = Wqb + (size_t)DIMC * DIMC;
  bf16* Wvb = Wkb + (size_t)DIMC * DIMC;
  bf16* Wob = Wvb + (size_t)DIMC * DIMC;
  bf16* Qb  = Wob + (size_t)DIMC * DIMC;
  bf16* Kb  = Qb  + (size_t)MTOT * DIMC;
  bf16* Vb  = Kb  + (size_t)MTOT * DIMC;
  bf16* Vt  = Vb  + (size_t)MTOT * DIMC;
  bf16* Cb  = Vb;  // alias: V dead once Vt exists

  const int nX = MTOT * DIMC, nW = DIMC * DIMC;
  cvt_f32_bf16<<<(nX / 4 + 255) / 256, 256, 0, stream>>>(x,  Xb,  nX);
  cvt_f32_bf16<<<(nW / 4 + 255) / 256, 256, 0, stream>>>(qw, Wqb, nW);
  cvt_f32_bf16<<<(nW / 4 + 255) / 256, 256, 0, stream>>>(kw, Wkb, nW);
  cvt_f32_bf16<<<(nW / 4 + 255) / 256, 256, 0, stream>>>(vw, Wvb, nW);
  cvt_f32_bf16<<<(nW / 4 + 255) / 256, 256, 0, stream>>>(ow, Wob, nW);

  // fused QKV projections: Q=(X Wq^T + bq)*0.125*log2e, K, V
  gemm_bt<true><<<dim3(32, 8, 3), 256, 0, stream>>>(
      Xb, Wqb, Wkb, Wvb, qb, kb, vb, Qb, Kb, Vb, 0.125f * LOG2E);

  transpose_v<<<dim3(QL / 64, 32), 256, 0, stream>>>(Vb, Vt);

  attn_fwd<<<1024, 128, 0, stream>>>(Qb, Kb, Vt, mask, Cb);

  // output projection (fp32 out)
  gemm_bt<false><<<dim3(32, 8, 1), 256, 0, stream>>>(
      Cb, Wob, Wob, Wob, ob, ob, ob, out, out, out, 1.0f);
}